// Round 10
// baseline (600.946 us; speedup 1.0000x reference)
//
#include <hip/hip_runtime.h>

#define N_NODES   100000
#define N_EDGES   1600000
#define CH        64
#define N_LAYERS  3
#define NUM_GRAPHS 2048
#define BN_EPS    1e-5f
#define NSLICE    4               // scatter slice groups (dst-space partition)
#define SLICE_SZ  25000           // N_NODES / NSLICE (exact)

#define NP        100096          // N_NODES padded to 391*256
#define NBLK1     391             // ceil(100000/256)
#define LDSTRIDE  65              // 64+1: (65*lane+k)%32 = (lane+k)%32, conflict-free

// ---------------------------------------------------------------------------
// CSR build: deg histogram -> exclusive scan -> edge scatter (src ids by dst)
// ---------------------------------------------------------------------------
__global__ __launch_bounds__(256) void hist_kernel(
    const int* __restrict__ dst, int* __restrict__ deg)
{
    int e = blockIdx.x * 256 + threadIdx.x;
    if (e < N_EDGES) atomicAdd(&deg[dst[e]], 1);
}

__global__ __launch_bounds__(256) void scan1_kernel(
    const int* __restrict__ deg, int* __restrict__ rowptr, int* __restrict__ blockSums)
{
    __shared__ int tmp[256];
    int t = threadIdx.x;
    int i = blockIdx.x * 256 + t;
    int v = (i < N_NODES) ? deg[i] : 0;
    tmp[t] = v;
    __syncthreads();
    for (int off = 1; off < 256; off <<= 1) {
        int a = (t >= off) ? tmp[t - off] : 0;
        __syncthreads();
        tmp[t] += a;
        __syncthreads();
    }
    if (i < N_NODES) rowptr[i] = tmp[t] - v;      // exclusive
    if (t == 255) blockSums[blockIdx.x] = tmp[255];
}

__global__ __launch_bounds__(512) void scan2_kernel(
    const int* __restrict__ blockSums, int* __restrict__ blockPrefix)
{
    __shared__ int tmp[512];
    int t = threadIdx.x;
    int v = (t < NBLK1) ? blockSums[t] : 0;
    tmp[t] = v;
    __syncthreads();
    for (int off = 1; off < 512; off <<= 1) {
        int a = (t >= off) ? tmp[t - off] : 0;
        __syncthreads();
        tmp[t] += a;
        __syncthreads();
    }
    if (t < NBLK1) blockPrefix[t] = tmp[t] - v;   // exclusive
}

__global__ __launch_bounds__(256) void scan3_kernel(
    int* __restrict__ rowptr, const int* __restrict__ blockPrefix)
{
    int i = blockIdx.x * 256 + threadIdx.x;
    if (i < N_NODES) rowptr[i] += blockPrefix[blockIdx.x];
}

// Slice-partitioned edge scatter. Bumps rowptr IN PLACE (no cursor array):
// after this kernel rowptr[n] = row END; aggregate uses [end-deg, end).
// Each of NSLICE block-groups scans all edges, writes only its dst slice
// (1.6 MB eidx region -> L2-resident per group).
__global__ __launch_bounds__(256) void scatter_edges_kernel(
    const int* __restrict__ src, const int* __restrict__ dst,
    int* __restrict__ rowptr, int* __restrict__ eidx)
{
    const int grp = blockIdx.x & (NSLICE - 1);
    const int ib  = blockIdx.x / NSLICE;
    const int nbx = gridDim.x / NSLICE;
    const int lo  = grp * SLICE_SZ;
    const int hi  = lo + SLICE_SZ;
    for (int e = ib * 256 + threadIdx.x; e < N_EDGES; e += nbx * 256) {
        int d = dst[e];
        if (d >= lo && d < hi) {
            int pos = atomicAdd(&rowptr[d], 1);
            eidx[pos] = src[e];
        }
    }
}

// ---------------------------------------------------------------------------
// Aggregate (pull): h[n] = x[n] + sum_{j->n} x[j].
// Thread = (node, float4 channel group): 1.6M threads, max TLP, 16 B/lane.
// rowptr[n] is the row END (post-scatter); start = end - deg[n].
// ---------------------------------------------------------------------------
__global__ __launch_bounds__(256) void aggregate_kernel(
    const float* __restrict__ xin,
    const int*   __restrict__ rowptr, const int* __restrict__ deg,
    const int*   __restrict__ eidx,
    float*       __restrict__ h)
{
    int tid = blockIdx.x * 256 + threadIdx.x;
    if (tid >= N_NODES * 16) return;
    int n  = tid >> 4;
    int cg = tid & 15;

    const float4* xv = (const float4*)xin;
    float4 acc = xv[(size_t)n * 16 + cg];

    int end = rowptr[n];
    int e   = end - deg[n];
    for (; e + 4 <= end; e += 4) {
        int s0 = eidx[e + 0], s1 = eidx[e + 1], s2 = eidx[e + 2], s3 = eidx[e + 3];
        float4 a = xv[(size_t)s0 * 16 + cg];
        float4 b = xv[(size_t)s1 * 16 + cg];
        float4 c = xv[(size_t)s2 * 16 + cg];
        float4 d = xv[(size_t)s3 * 16 + cg];
        acc.x += a.x; acc.y += a.y; acc.z += a.z; acc.w += a.w;
        acc.x += b.x; acc.y += b.y; acc.z += b.z; acc.w += b.w;
        acc.x += c.x; acc.y += c.y; acc.z += c.z; acc.w += c.w;
        acc.x += d.x; acc.y += d.y; acc.z += d.z; acc.w += d.w;
    }
    for (; e < end; ++e) {
        float4 a = xv[(size_t)eidx[e] * 16 + cg];
        acc.x += a.x; acc.y += a.y; acc.z += a.z; acc.w += a.w;
    }
    ((float4*)h)[(size_t)n * 16 + cg] = acc;
}

// ---------------------------------------------------------------------------
// MLP, node-per-lane with LDS-resident activation row (verified r9: no
// scratch, no bank conflicts). In-place safe.
// ---------------------------------------------------------------------------
__global__ __launch_bounds__(128) void mlp_kernel(
    const float* __restrict__ hin,
    const float* __restrict__ W1,   const float* __restrict__ b1,
    const float* __restrict__ gamma,const float* __restrict__ beta,
    const float* __restrict__ mean, const float* __restrict__ var,
    const float* __restrict__ W2,   const float* __restrict__ b2,
    float* __restrict__ xout)
{
    __shared__ float sbuf[2 * 64 * LDSTRIDE];   // 33,280 B

    const int lane = threadIdx.x & 63;
    const int wv   = threadIdx.x >> 6;
    const int gw   = blockIdx.x * 2 + wv;       // global wave = 64-node block
    float* lds = sbuf + wv * (64 * LDSTRIDE);

    const long long base = (long long)gw * 64 * CH;      // float offset
    const long long totF = (long long)N_NODES * CH;

    // ---- stage 64x64 row-block global -> LDS (coalesced float4) ----
    const float4* gin4 = (const float4*)(hin + base);
    for (int i = lane; i < 1024; i += 64) {
        int fo = i * 4;
        float4 v = make_float4(0.f, 0.f, 0.f, 0.f);
        if (base + fo + 3 < totF) v = gin4[i];
        int row = fo >> 6, col = fo & 63;
        float* p = lds + row * LDSTRIDE + col;
        p[0] = v.x; p[1] = v.y; p[2] = v.z; p[3] = v.w;
    }
    __syncthreads();

    float* myrow = lds + lane * LDSTRIDE;

    // ---- GEMM1: a[j] = b1[j] + sum_k h[k]*W1[k][j] ----
    float a[CH];
    #pragma unroll
    for (int j = 0; j < CH; ++j) a[j] = b1[j];
    for (int k = 0; k < CH; ++k) {              // rolled: hk via LDS read
        float hk = myrow[k];
        const float* wrow = W1 + k * CH;        // lane-uniform -> s_load
        #pragma unroll
        for (int j = 0; j < CH; ++j)
            a[j] = fmaf(hk, wrow[j], a[j]);
    }

    // ---- BN(eval) + ReLU -> own LDS row ----
    #pragma unroll
    for (int j = 0; j < CH; ++j) {
        float sc = gamma[j] * rsqrtf(var[j] + BN_EPS);
        float sh = beta[j] - mean[j] * sc;
        myrow[j] = fmaxf(fmaf(a[j], sc, sh), 0.0f);
    }

    // ---- GEMM2: c[j] = b2[j] + sum_k t[k]*W2[k][j] ----
    float c[CH];
    #pragma unroll
    for (int j = 0; j < CH; ++j) c[j] = b2[j];
    for (int k = 0; k < CH; ++k) {
        float tk = myrow[k];
        const float* wrow = W2 + k * CH;
        #pragma unroll
        for (int j = 0; j < CH; ++j)
            c[j] = fmaf(tk, wrow[j], c[j]);
    }

    // ---- ReLU -> own LDS row, then coalesced float4 store ----
    #pragma unroll
    for (int j = 0; j < CH; ++j)
        myrow[j] = fmaxf(c[j], 0.0f);
    __syncthreads();

    float4* gout4 = (float4*)(xout + base);
    for (int i = lane; i < 1024; i += 64) {
        int fo = i * 4;
        if (base + fo + 3 < totF) {
            int row = fo >> 6, col = fo & 63;
            const float* p = lds + row * LDSTRIDE + col;
            gout4[i] = make_float4(p[0], p[1], p[2], p[3]);
        }
    }
}

// ---------------------------------------------------------------------------
// Fused pool+head: wave per graph. batch is SORTED -> binary search bounds,
// mean in registers, MLP via LDS weights, softmax(2). pooled never hits HBM.
// ---------------------------------------------------------------------------
__global__ __launch_bounds__(256) void pool_head_kernel(
    const float* __restrict__ x, const int* __restrict__ batch,
    const float* __restrict__ W1, const float* __restrict__ b1,
    const float* __restrict__ W2, const float* __restrict__ b2,
    float* __restrict__ out)
{
    __shared__ float w1[CH * CH];
    __shared__ float b1s[CH];
    __shared__ float w2s[CH * 2];

    for (int i = threadIdx.x; i < CH * CH; i += blockDim.x) w1[i] = W1[i];
    if (threadIdx.x < CH)     b1s[threadIdx.x] = b1[threadIdx.x];
    if (threadIdx.x < CH * 2) w2s[threadIdx.x] = W2[threadIdx.x];
    __syncthreads();

    const int lane = threadIdx.x & 63;
    const int g = blockIdx.x * (blockDim.x >> 6) + (threadIdx.x >> 6);
    if (g >= NUM_GRAPHS) return;

    // segment bounds via binary search (batch sorted)
    int lo = 0, hi = N_NODES;
    while (lo < hi) { int mid = (lo + hi) >> 1; if (batch[mid] < g) lo = mid + 1; else hi = mid; }
    int start = lo;
    lo = start; hi = N_NODES;
    while (lo < hi) { int mid = (lo + hi) >> 1; if (batch[mid] < g + 1) lo = mid + 1; else hi = mid; }
    int end = lo;

    float s = 0.0f;
    for (int n = start; n < end; ++n) s += x[(size_t)n * CH + lane];
    int c = end - start;
    float p = s / (float)(c > 0 ? c : 1);

    float acc = b1s[lane];
    #pragma unroll
    for (int k = 0; k < CH; ++k)
        acc = fmaf(__shfl(p, k, 64), w1[k * CH + lane], acc);
    float h = fmaxf(acc, 0.0f);

    float l0 = h * w2s[lane * 2 + 0];
    float l1 = h * w2s[lane * 2 + 1];
    #pragma unroll
    for (int off = 32; off > 0; off >>= 1) {
        l0 += __shfl_xor(l0, off, 64);
        l1 += __shfl_xor(l1, off, 64);
    }
    if (lane == 0) {
        l0 += b2[0];
        l1 += b2[1];
        float m  = fmaxf(l0, l1);
        float e0 = expf(l0 - m), e1 = expf(l1 - m);
        float sm = e0 + e1;
        out[(size_t)g * 2 + 0] = e0 / sm;
        out[(size_t)g * 2 + 1] = e1 / sm;
    }
}

extern "C" void kernel_launch(void* const* d_in, const int* in_sizes, int n_in,
                              void* d_out, int out_size, void* d_ws, size_t ws_size,
                              hipStream_t stream)
{
    const float* x      = (const float*)d_in[0];
    const int*   ei     = (const int*)  d_in[1];
    const int*   src    = ei;
    const int*   dst    = ei + N_EDGES;
    const int*   batch  = (const int*)  d_in[2];
    const float* convW1 = (const float*)d_in[3];
    const float* convb1 = (const float*)d_in[4];
    const float* gamma  = (const float*)d_in[5];
    const float* beta   = (const float*)d_in[6];
    const float* mean   = (const float*)d_in[7];
    const float* var    = (const float*)d_in[8];
    const float* convW2 = (const float*)d_in[9];
    const float* convb2 = (const float*)d_in[10];
    const float* mlpW1  = (const float*)d_in[11];
    const float* mlpb1  = (const float*)d_in[12];
    const float* mlpW2  = (const float*)d_in[13];
    const float* mlpb2  = (const float*)d_in[14];
    float* out = (float*)d_out;

    // ---- workspace layout ----
    int* deg         = (int*)d_ws;                 // NP
    int* rowptr      = deg + NP;                   // NP (becomes END ptrs)
    int* blockSums   = rowptr + NP;                // 512
    int* blockPrefix = blockSums + 512;            // 512
    int* eidx        = blockPrefix + 512;          // N_EDGES
    float* xA        = (float*)(eidx + N_EDGES);   // N_NODES*CH
    float* xB        = xA + (size_t)N_NODES * CH;  // N_NODES*CH

    // ---- CSR build ----
    hipMemsetAsync(deg, 0, NP * sizeof(int), stream);
    hist_kernel<<<(N_EDGES + 255) / 256, 256, 0, stream>>>(dst, deg);
    scan1_kernel<<<NBLK1, 256, 0, stream>>>(deg, rowptr, blockSums);
    scan2_kernel<<<1, 512, 0, stream>>>(blockSums, blockPrefix);
    scan3_kernel<<<NBLK1, 256, 0, stream>>>(rowptr, blockPrefix);
    scatter_edges_kernel<<<2048, 256, 0, stream>>>(src, dst, rowptr, eidx);

    const int aggGrid = (N_NODES * 16 + 255) / 256;   // 6250 blocks
    const int mlpGrid = (N_NODES + 127) / 128;        // 782 blocks (2 waves each)

    // ---- 3 GIN layers: aggregate (TLP gather) then MLP (in-place) ----
    aggregate_kernel<<<aggGrid, 256, 0, stream>>>(x, rowptr, deg, eidx, xA);
    mlp_kernel<<<mlpGrid, 128, 0, stream>>>(xA,
        convW1, convb1, gamma, beta, mean, var, convW2, convb2, xA);
    aggregate_kernel<<<aggGrid, 256, 0, stream>>>(xA, rowptr, deg, eidx, xB);
    mlp_kernel<<<mlpGrid, 128, 0, stream>>>(xB,
        convW1 + CH*CH, convb1 + CH, gamma + CH, beta + CH, mean + CH, var + CH,
        convW2 + CH*CH, convb2 + CH, xB);
    aggregate_kernel<<<aggGrid, 256, 0, stream>>>(xB, rowptr, deg, eidx, xA);
    mlp_kernel<<<mlpGrid, 128, 0, stream>>>(xA,
        convW1 + 2*CH*CH, convb1 + 2*CH, gamma + 2*CH, beta + 2*CH, mean + 2*CH,
        var + 2*CH, convW2 + 2*CH*CH, convb2 + 2*CH, xA);

    // ---- fused pool + head ----
    pool_head_kernel<<<NUM_GRAPHS / 4, 256, 0, stream>>>(
        xA, batch, mlpW1, mlpb1, mlpW2, mlpb2, out);
}